// Round 1
// baseline (1445.651 us; speedup 1.0000x reference)
//
#include <hip/hip_runtime.h>
#include <cstdint>
#include <cstddef>

#define TTOK 4096
#define HID  2048
#define NEXP 16
#define KTOP 4
#define IMID 1408
#define SIM  2816

typedef __attribute__((ext_vector_type(4))) float f32x4;
typedef __attribute__((ext_vector_type(8))) short s16x8;
typedef __attribute__((ext_vector_type(4))) short s16x4;

// ---------------- ws layout (bytes) ----------------
#define OFF_XB   0UL
#define OFF_WGB  (OFF_XB  + 16777216UL)   // 16*1408*2048*2
#define OFF_WUB  (OFF_WGB + 92274688UL)
#define OFF_WDB  (OFF_WUB + 92274688UL)
#define OFF_SWG  (OFF_WDB + 92274688UL)
#define OFF_SWU  (OFF_SWG + 11534336UL)
#define OFF_SWD  (OFF_SWU + 11534336UL)
#define OFF_TKI  (OFF_SWD + 11534336UL)
#define OFF_TKW  (OFF_TKI + 65536UL)
#define OFF_CNT  (OFF_TKW + 65536UL)      // 16 ints
#define OFF_OFFS (OFF_CNT + 64UL)         // 16 ints
#define OFF_CUR  (OFF_OFFS + 64UL)        // 16 ints
#define OFF_LIST (OFF_CUR + 64UL)         // 16384 ints
#define OFF_ACT  (OFF_LIST + 65536UL)     // 16384*1408 bf16
#define OFF_DOUT (OFF_ACT + 46137344UL)   // 16384*2048 bf16
#define OFF_SACT OFF_ACT                  // aliases act (used after routed down)
// total ~442 MB

__device__ __forceinline__ unsigned short f2bf(float f) {
    unsigned int u = __float_as_uint(f);
    return (unsigned short)((u + 0x7FFFu + ((u >> 16) & 1u)) >> 16);
}
__device__ __forceinline__ float bf2f(unsigned short s) {
    return __uint_as_float(((unsigned int)s) << 16);
}
__device__ __forceinline__ void gll16(const void* g, void* l) {
    __builtin_amdgcn_global_load_lds((const __attribute__((address_space(1))) unsigned int*)g,
                                     (__attribute__((address_space(3))) unsigned int*)l, 16, 0, 0);
}

// ---------------- cast fp32 -> bf16 ----------------
__global__ __launch_bounds__(256) void cast_k(const float* __restrict__ in,
                                              unsigned short* __restrict__ out, long n) {
    long i = ((long)blockIdx.x * 256 + threadIdx.x) * 4;
    if (i >= n) return;
    f32x4 v = *(const f32x4*)(in + i);
    s16x4 o;
    o.x = (short)f2bf(v.x); o.y = (short)f2bf(v.y);
    o.z = (short)f2bf(v.z); o.w = (short)f2bf(v.w);
    *(s16x4*)(out + i) = o;
}

// ---------------- routing: softmax + top4 ----------------
__global__ __launch_bounds__(64) void route_k(const float* __restrict__ x,
                                              const float* __restrict__ gw,
                                              int* __restrict__ tki, float* __restrict__ tkw) {
    int t = blockIdx.x;
    int lane = threadIdx.x;
    const float* xr = x + (size_t)t * HID;
    float acc[NEXP];
#pragma unroll
    for (int e = 0; e < NEXP; e++) acc[e] = 0.f;
    for (int h = lane; h < HID; h += 64) {
        float xv = xr[h];
#pragma unroll
        for (int e = 0; e < NEXP; e++) acc[e] += xv * gw[e * HID + h];
    }
#pragma unroll
    for (int e = 0; e < NEXP; e++) {
        float v = acc[e];
#pragma unroll
        for (int off = 32; off; off >>= 1) v += __shfl_xor(v, off);
        acc[e] = v;
    }
    if (lane == 0) {
        float mx = acc[0];
#pragma unroll
        for (int e = 1; e < NEXP; e++) mx = fmaxf(mx, acc[e]);
        float s = 0.f, p[NEXP];
#pragma unroll
        for (int e = 0; e < NEXP; e++) { p[e] = expf(acc[e] - mx); s += p[e]; }
#pragma unroll
        for (int e = 0; e < NEXP; e++) p[e] /= s;
        float wsum = 0.f; int idx[KTOP]; float wv[KTOP];
#pragma unroll
        for (int k = 0; k < KTOP; k++) {
            int bi = 0; float bv = -1.f;
#pragma unroll
            for (int e = 0; e < NEXP; e++) if (p[e] > bv) { bv = p[e]; bi = e; }
            idx[k] = bi; wv[k] = bv; p[bi] = -2.f; wsum += bv;
        }
#pragma unroll
        for (int k = 0; k < KTOP; k++) { tki[t * 4 + k] = idx[k]; tkw[t * 4 + k] = wv[k] / wsum; }
    }
}

__global__ __launch_bounds__(256) void count_k(const int* __restrict__ tki, int* __restrict__ cnt) {
    int i = blockIdx.x * 256 + threadIdx.x;
    if (i < TTOK * KTOP) atomicAdd(&cnt[tki[i]], 1);
}
__global__ void scan_k(const int* __restrict__ cnt, int* __restrict__ offs, int* __restrict__ cur) {
    if (threadIdx.x == 0) {
        int s = 0;
        for (int e = 0; e < NEXP; e++) { offs[e] = s; cur[e] = s; s += cnt[e]; }
    }
}
__global__ __launch_bounds__(256) void scatter_k(const int* __restrict__ tki, int* __restrict__ cur,
                                                 int* __restrict__ list) {
    int i = blockIdx.x * 256 + threadIdx.x;
    if (i < TTOK * KTOP) {
        int e = tki[i];
        int p = atomicAdd(&cur[e], 1);
        list[p] = i;   // i = t*4+k
    }
}

// ---------------- grouped GEMM ----------------
// MODE 0: routed gate+up  (A=xb gathered, K=2048, N=1408, silu(g)*u -> act[pos])
// MODE 1: shared gate+up  (A=xb,          K=2048, N=2816, silu(g)*u -> sact[row])
// MODE 2: routed down     (A=act,         K=1408, N=2048, *tkw -> dout[entry])
// MODE 3: shared down     (A=sact,        K=2816, N=2048, fp32 -> y[row])
template <int MODE>
__global__ __launch_bounds__(256, 2) void gemm_k(const unsigned short* __restrict__ A,
                                                 const unsigned short* __restrict__ B0,
                                                 const unsigned short* __restrict__ B1,
                                                 void* __restrict__ C,
                                                 const int* __restrict__ counts,
                                                 const int* __restrict__ offs,
                                                 const int* __restrict__ list,
                                                 const float* __restrict__ tkw) {
    constexpr bool GU = (MODE == 0 || MODE == 1);
    constexpr bool ROUTED = (MODE == 0 || MODE == 2);
    constexpr int KD = (MODE == 2) ? IMID : ((MODE == 3) ? SIM : HID);
    constexpr int ND = (MODE == 0) ? IMID : ((MODE == 1) ? SIM : HID);
    constexpr int NB = ND / 128;

    int tid = threadIdx.x, lane = tid & 63, wv = tid >> 6;
    int bid = blockIdx.x;
    int e = 0, mb, nb, cnt, off;
    if (ROUTED) {
        e = bid / (32 * NB);
        int r = bid - e * (32 * NB);
        mb = r / NB; nb = r - mb * NB;
        cnt = counts[e]; off = offs[e];
        if (mb * 128 >= cnt) return;
    } else {
        mb = bid / NB; nb = bid - mb * NB; cnt = TTOK; off = 0;
    }

    const unsigned short* b0 = B0;
    const unsigned short* b1 = B1;
    if (MODE == 0) { b0 += (size_t)e * IMID * HID; b1 += (size_t)e * IMID * HID; }
    if (MODE == 2) { b0 += (size_t)e * HID * IMID; }

    // staging row pointers: thread covers LDS rows q*64 + tid/4, inner 16B chunk (tid&3)
    const char* arow[2];
    const char* brow0[2];
    const char* brow1[2];
#pragma unroll
    for (int q = 0; q < 2; q++) {
        int r = mb * 128 + q * 64 + (tid >> 2);
        int rr = r < cnt ? r : cnt - 1;
        if (MODE == 0) { int tk = list[off + rr] >> 2; arow[q] = (const char*)(A + (size_t)tk * HID); }
        if (MODE == 1) { arow[q] = (const char*)(A + (size_t)rr * HID); }
        if (MODE == 2) { arow[q] = (const char*)(A + (size_t)(off + rr) * IMID); }
        if (MODE == 3) { arow[q] = (const char*)(A + (size_t)rr * SIM); }
        int rn = nb * 128 + q * 64 + (tid >> 2);
        brow0[q] = (const char*)(b0 + (size_t)rn * KD);
        if (GU) brow1[q] = (const char*)(b1 + (size_t)rn * KD);
    }

    constexpr int SBYTES = GU ? 24576 : 16384;
    __shared__ __align__(64) char smem[SBYTES];
    int inner = (lane & 3) * 16;
    char* ldsA  = smem + wv * 1024;
    char* ldsB0 = smem + 8192 + wv * 1024;
    char* ldsB1 = smem + 16384 + wv * 1024;

    f32x4 acc0[4][4], acc1[4][4];
#pragma unroll
    for (int i = 0; i < 4; i++)
#pragma unroll
        for (int j = 0; j < 4; j++) {
            acc0[i][j] = (f32x4){0.f, 0.f, 0.f, 0.f};
            acc1[i][j] = (f32x4){0.f, 0.f, 0.f, 0.f};
        }

    int wm = wv >> 1, wn = wv & 1;
    const unsigned short* rA  = (const unsigned short*)smem +
                                (wm * 64 + (lane & 15)) * 32 + ((lane >> 4) << 3);
    const unsigned short* rB0 = (const unsigned short*)(smem + 8192) +
                                (wn * 64 + (lane & 15)) * 32 + ((lane >> 4) << 3);
    const unsigned short* rB1 = (const unsigned short*)(smem + 16384) +
                                (wn * 64 + (lane & 15)) * 32 + ((lane >> 4) << 3);

    for (int k0 = 0; k0 < KD; k0 += 32) {
        size_t kb = (size_t)k0 * 2 + inner;
#pragma unroll
        for (int q = 0; q < 2; q++) {
            gll16(arow[q] + kb, ldsA + q * 4096);
            gll16(brow0[q] + kb, ldsB0 + q * 4096);
            if (GU) gll16(brow1[q] + kb, ldsB1 + q * 4096);
        }
        asm volatile("s_waitcnt vmcnt(0)" ::: "memory");
        __syncthreads();

        s16x8 af[4], bf0[4], bf1[4];
#pragma unroll
        for (int i = 0; i < 4; i++) {
            af[i] = *(const s16x8*)(rA + i * 16 * 32);
            bf0[i] = *(const s16x8*)(rB0 + i * 16 * 32);
            if (GU) bf1[i] = *(const s16x8*)(rB1 + i * 16 * 32);
        }
#pragma unroll
        for (int mi = 0; mi < 4; mi++)
#pragma unroll
            for (int ni = 0; ni < 4; ni++) {
                acc0[mi][ni] = __builtin_amdgcn_mfma_f32_16x16x32_bf16(af[mi], bf0[ni], acc0[mi][ni], 0, 0, 0);
                if (GU)
                    acc1[mi][ni] = __builtin_amdgcn_mfma_f32_16x16x32_bf16(af[mi], bf1[ni], acc1[mi][ni], 0, 0, 0);
            }
        __syncthreads();
    }

    int c0 = nb * 128 + wn * 64 + (lane & 15);
    int rb = mb * 128 + wm * 64 + ((lane >> 4) << 2);

    if (GU) {
        unsigned short* outp = (unsigned short*)C;
#pragma unroll
        for (int mi = 0; mi < 4; mi++)
#pragma unroll
            for (int j = 0; j < 4; j++) {
                int gr = rb + mi * 16 + j;
                if (gr < cnt) {
                    size_t orow = (size_t)(ROUTED ? (off + gr) : gr);
                    unsigned short* op = outp + orow * ND + c0;
#pragma unroll
                    for (int ni = 0; ni < 4; ni++) {
                        float g = acc0[mi][ni][j], u = acc1[mi][ni][j];
                        float v = (g / (1.f + expf(-g))) * u;
                        op[ni * 16] = f2bf(v);
                    }
                }
            }
    } else if (MODE == 2) {
        unsigned short* outp = (unsigned short*)C;
#pragma unroll
        for (int mi = 0; mi < 4; mi++)
#pragma unroll
            for (int j = 0; j < 4; j++) {
                int gr = rb + mi * 16 + j;
                if (gr < cnt) {
                    int en = list[off + gr];
                    float w = tkw[en];
                    unsigned short* op = outp + (size_t)en * HID + c0;
#pragma unroll
                    for (int ni = 0; ni < 4; ni++) op[ni * 16] = f2bf(acc0[mi][ni][j] * w);
                }
            }
    } else {
        float* outp = (float*)C;
#pragma unroll
        for (int mi = 0; mi < 4; mi++)
#pragma unroll
            for (int j = 0; j < 4; j++) {
                int gr = rb + mi * 16 + j;
                float* op = outp + (size_t)gr * HID + c0;
#pragma unroll
                for (int ni = 0; ni < 4; ni++) op[ni * 16] = acc0[mi][ni][j];
            }
    }
}

// ---------------- combine: y += sum_k dout[t*4+k] ----------------
__global__ __launch_bounds__(256) void combine_k(const unsigned short* __restrict__ dout,
                                                 float* __restrict__ y) {
    long i = ((long)blockIdx.x * 256 + threadIdx.x) * 4;
    int t = (int)(i >> 11);
    int h = (int)(i & 2047);
    f32x4 acc = *(f32x4*)(y + i);
#pragma unroll
    for (int k = 0; k < 4; k++) {
        s16x4 dv = *(const s16x4*)(dout + (((size_t)t * 4 + k) << 11) + h);
        acc.x += bf2f((unsigned short)dv.x);
        acc.y += bf2f((unsigned short)dv.y);
        acc.z += bf2f((unsigned short)dv.z);
        acc.w += bf2f((unsigned short)dv.w);
    }
    *(f32x4*)(y + i) = acc;
}

extern "C" void kernel_launch(void* const* d_in, const int* in_sizes, int n_in,
                              void* d_out, int out_size, void* d_ws, size_t ws_size,
                              hipStream_t stream) {
    const float* x   = (const float*)d_in[0];
    const float* gw  = (const float*)d_in[1];
    const float* wg  = (const float*)d_in[2];
    const float* wu  = (const float*)d_in[3];
    const float* wd  = (const float*)d_in[4];
    const float* swg = (const float*)d_in[5];
    const float* swu = (const float*)d_in[6];
    const float* swd = (const float*)d_in[7];

    char* ws = (char*)d_ws;
    unsigned short* xb   = (unsigned short*)(ws + OFF_XB);
    unsigned short* wgb  = (unsigned short*)(ws + OFF_WGB);
    unsigned short* wub  = (unsigned short*)(ws + OFF_WUB);
    unsigned short* wdb  = (unsigned short*)(ws + OFF_WDB);
    unsigned short* swgb = (unsigned short*)(ws + OFF_SWG);
    unsigned short* swub = (unsigned short*)(ws + OFF_SWU);
    unsigned short* swdb = (unsigned short*)(ws + OFF_SWD);
    int*   tki  = (int*)(ws + OFF_TKI);
    float* tkw  = (float*)(ws + OFF_TKW);
    int*   cnt  = (int*)(ws + OFF_CNT);
    int*   offs = (int*)(ws + OFF_OFFS);
    int*   cur  = (int*)(ws + OFF_CUR);
    int*   list = (int*)(ws + OFF_LIST);
    unsigned short* act  = (unsigned short*)(ws + OFF_ACT);
    unsigned short* dout = (unsigned short*)(ws + OFF_DOUT);
    unsigned short* sact = (unsigned short*)(ws + OFF_SACT);
    float* y = (float*)d_out;

    hipMemsetAsync(ws + OFF_CNT, 0, 192, stream);

    auto cast = [&](const float* in, unsigned short* out, long n) {
        int blocks = (int)((n / 4 + 255) / 256);
        cast_k<<<blocks, 256, 0, stream>>>(in, out, n);
    };
    cast(x,   xb,   (long)TTOK * HID);
    cast(wg,  wgb,  (long)NEXP * IMID * HID);
    cast(wu,  wub,  (long)NEXP * IMID * HID);
    cast(wd,  wdb,  (long)NEXP * HID * IMID);
    cast(swg, swgb, (long)SIM * HID);
    cast(swu, swub, (long)SIM * HID);
    cast(swd, swdb, (long)HID * SIM);

    route_k<<<TTOK, 64, 0, stream>>>(x, gw, tki, tkw);
    count_k<<<TTOK * KTOP / 256, 256, 0, stream>>>(tki, cnt);
    scan_k<<<1, 64, 0, stream>>>(cnt, offs, cur);
    scatter_k<<<TTOK * KTOP / 256, 256, 0, stream>>>(tki, cur, list);

    // routed gate+up -> act ; routed down -> dout
    gemm_k<0><<<NEXP * 32 * (IMID / 128), 256, 0, stream>>>(xb, wgb, wub, act, cnt, offs, list, tkw);
    gemm_k<2><<<NEXP * 32 * (HID / 128), 256, 0, stream>>>(act, wdb, nullptr, dout, cnt, offs, list, tkw);
    // shared experts (sact aliases act, safe after routed down completed)
    gemm_k<1><<<(TTOK / 128) * (SIM / 128), 256, 0, stream>>>(xb, swgb, swub, sact, cnt, offs, list, tkw);
    gemm_k<3><<<(TTOK / 128) * (HID / 128), 256, 0, stream>>>(sact, swdb, nullptr, (void*)y, cnt, offs, list, tkw);

    combine_k<<<TTOK * HID / 4 / 256, 256, 0, stream>>>(dout, y);
}